// Round 1
// baseline (778.459 us; speedup 1.0000x reference)
//
#include <hip/hip_runtime.h>
#include <hip/hip_bf16.h>
#include <stdint.h>

typedef __attribute__((ext_vector_type(8))) short bf16x8;
typedef __attribute__((ext_vector_type(4))) float f32x4;

typedef const __attribute__((address_space(1))) void* gas_ptr;
typedef __attribute__((address_space(3))) void* lds_ptr_t;

__device__ __forceinline__ unsigned short f32_to_bf16_rtn(float x) {
    unsigned u = __float_as_uint(x);
    u += 0x7FFFu + ((u >> 16) & 1u);
    return (unsigned short)(u >> 16);
}
__device__ __forceinline__ float bf16_bits_to_f32(unsigned short h) {
    return __uint_as_float(((unsigned)h) << 16);
}

// ---------------------------------------------------------------------------
// Kernel 1: split fp32 inputs into hi/lo bf16 pairs (a = hi + lo, err ~2^-17)
// ---------------------------------------------------------------------------
__global__ __launch_bounds__(256) void split_hi_lo(
    const float* __restrict__ A, const float* __restrict__ B,
    unsigned short* __restrict__ Ahi, unsigned short* __restrict__ Alo,
    unsigned short* __restrict__ Bhi, unsigned short* __restrict__ Blo, int n4)
{
    int i = blockIdx.x * 256 + threadIdx.x;
    if (i >= n4) return;
    float4 a = ((const float4*)A)[i];
    float4 b = ((const float4*)B)[i];
    ushort4 h, l;

    h.x = f32_to_bf16_rtn(a.x); l.x = f32_to_bf16_rtn(a.x - bf16_bits_to_f32(h.x));
    h.y = f32_to_bf16_rtn(a.y); l.y = f32_to_bf16_rtn(a.y - bf16_bits_to_f32(h.y));
    h.z = f32_to_bf16_rtn(a.z); l.z = f32_to_bf16_rtn(a.z - bf16_bits_to_f32(h.z));
    h.w = f32_to_bf16_rtn(a.w); l.w = f32_to_bf16_rtn(a.w - bf16_bits_to_f32(h.w));
    ((ushort4*)Ahi)[i] = h; ((ushort4*)Alo)[i] = l;

    h.x = f32_to_bf16_rtn(b.x); l.x = f32_to_bf16_rtn(b.x - bf16_bits_to_f32(h.x));
    h.y = f32_to_bf16_rtn(b.y); l.y = f32_to_bf16_rtn(b.y - bf16_bits_to_f32(h.y));
    h.z = f32_to_bf16_rtn(b.z); l.z = f32_to_bf16_rtn(b.z - bf16_bits_to_f32(h.z));
    h.w = f32_to_bf16_rtn(b.w); l.w = f32_to_bf16_rtn(b.w - bf16_bits_to_f32(h.w));
    ((ushort4*)Bhi)[i] = h; ((ushort4*)Blo)[i] = l;
}

// ---------------------------------------------------------------------------
// Kernel 2 (presplit, hot path): energies = A @ B^T, split-bf16 3-product GEMM.
// 16x16x32 mfma, 4x4 tiles/wave, 128x128 block, BK=32.
// XOR swizzle on 16B chunks (position p holds data chunk p ^ ((row>>1)&3)):
// r4 measured SQ_LDS_BANK_CONFLICT == 0 with this exact pattern.
// NO min-waves launch bound: r4's (256,4) forced 128-reg budget -> ~330 MB of
// scratch spill stores in the K-loop and a 470 us regression. Natural
// allocation (~84 VGPR + 64 AGPR) wins.
// NEW this round: T1 XCD-bijective blockIdx swizzle (nwg=4096, %8==0) so each
// XCD's L2 sees 8 consecutive bm-panels -> predict FETCH_SIZE 323 -> <200 MB.
// ---------------------------------------------------------------------------
__global__ __launch_bounds__(256) void gemm_presplit(
    const __hip_bfloat16* __restrict__ Ahi, const __hip_bfloat16* __restrict__ Alo,
    const __hip_bfloat16* __restrict__ Bhi, const __hip_bfloat16* __restrict__ Blo,
    float* __restrict__ out, int M, int N, int K)
{
    __shared__ char sm[32768];   // [0,8K)=Ahi [8K,16K)=Alo [16K,24K)=Bhi [24K,32K)=Blo
    const int tid  = threadIdx.x;
    const int lane = tid & 63;
    const int w    = tid >> 6;

    // T1 XCD-aware bijective remap of the linear workgroup id.
    const int gx  = (int)gridDim.x;
    const int nwg = gx * (int)gridDim.y;
    int lid = (int)blockIdx.y * gx + (int)blockIdx.x;
    if ((nwg & 7) == 0) lid = (lid & 7) * (nwg >> 3) + (lid >> 3);
    const int bm = lid / gx;
    const int bn = lid - bm * gx;

    const int wm = (w >> 1) * 64;
    const int wn = (w & 1) * 64;

    f32x4 acc[4][4] = {};

    // staging: thread owns LDS chunk (row=(c&1)*64 + tid>>2, pos=tid&3);
    // fetches source chunk (tid&3) ^ ((row>>1)&3) = (tid&3) ^ ((tid>>3)&3)
    const int sfetch = (tid & 3) ^ ((tid >> 3) & 3);
    const size_t offA = (size_t)(bm * 128 + (tid >> 2)) * K + sfetch * 8;
    const size_t offB = (size_t)(bn * 128 + (tid >> 2)) * K + sfetch * 8;
    const __hip_bfloat16* pAh = Ahi + offA;
    const __hip_bfloat16* pAl = Alo + offA;
    const __hip_bfloat16* pBh = Bhi + offB;
    const __hip_bfloat16* pBl = Blo + offB;
    const size_t half = (size_t)64 * K;   // +64 rows
    char* dst0 = sm + tid * 16;

    // read side: fragment chunk = lane>>4, swizzled: ^ ((lane>>1)&3)
    const int rA = lane & 15;
    const int ca = (lane >> 4) ^ ((lane >> 1) & 3);
    const char* aP = sm +         (wm + rA) * 64 + ca * 16;   // A-hi base
    const char* bP = sm + 16384 + (wn + rA) * 64 + ca * 16;   // B-hi base

    for (int k0 = 0; k0 < K; k0 += 32) {
        __syncthreads();
        __builtin_amdgcn_global_load_lds((gas_ptr)(pAh + k0),        (lds_ptr_t)(dst0),         16, 0, 0);
        __builtin_amdgcn_global_load_lds((gas_ptr)(pAh + half + k0), (lds_ptr_t)(dst0 + 4096),  16, 0, 0);
        __builtin_amdgcn_global_load_lds((gas_ptr)(pAl + k0),        (lds_ptr_t)(dst0 + 8192),  16, 0, 0);
        __builtin_amdgcn_global_load_lds((gas_ptr)(pAl + half + k0), (lds_ptr_t)(dst0 + 12288), 16, 0, 0);
        __builtin_amdgcn_global_load_lds((gas_ptr)(pBh + k0),        (lds_ptr_t)(dst0 + 16384), 16, 0, 0);
        __builtin_amdgcn_global_load_lds((gas_ptr)(pBh + half + k0), (lds_ptr_t)(dst0 + 20480), 16, 0, 0);
        __builtin_amdgcn_global_load_lds((gas_ptr)(pBl + k0),        (lds_ptr_t)(dst0 + 24576), 16, 0, 0);
        __builtin_amdgcn_global_load_lds((gas_ptr)(pBl + half + k0), (lds_ptr_t)(dst0 + 28672), 16, 0, 0);
        __syncthreads();

        bf16x8 bh[4], bl[4];
#pragma unroll
        for (int j = 0; j < 4; ++j) {
            bh[j] = *(const bf16x8*)(bP + j * 1024);
            bl[j] = *(const bf16x8*)(bP + j * 1024 + 8192);
        }
#pragma unroll
        for (int i = 0; i < 4; ++i) {
            bf16x8 ah = *(const bf16x8*)(aP + i * 1024);
            bf16x8 al = *(const bf16x8*)(aP + i * 1024 + 8192);
#pragma unroll
            for (int j = 0; j < 4; ++j) {
                acc[i][j] = __builtin_amdgcn_mfma_f32_16x16x32_bf16(ah, bh[j], acc[i][j], 0, 0, 0);
                acc[i][j] = __builtin_amdgcn_mfma_f32_16x16x32_bf16(al, bh[j], acc[i][j], 0, 0, 0);
                acc[i][j] = __builtin_amdgcn_mfma_f32_16x16x32_bf16(ah, bl[j], acc[i][j], 0, 0, 0);
            }
        }
    }

    // Epilogue: 16x16 C/D layout col=lane&15, row=(lane>>4)*4+reg (m89/m91)
    const int r0 = bm * 128 + wm + ((lane >> 4) << 2);
    const int c0 = bn * 128 + wn + rA;
#pragma unroll
    for (int i = 0; i < 4; ++i)
#pragma unroll
        for (int j = 0; j < 4; ++j)
#pragma unroll
            for (int r = 0; r < 4; ++r)
                out[(size_t)(r0 + i * 16 + r) * N + (c0 + j * 16)] = acc[i][j][r];
}

// ---------------------------------------------------------------------------
// Kernel 2b (fallback, ws too small — not expected to run): inline split.
// ---------------------------------------------------------------------------
__global__ __launch_bounds__(256) void gemm_fallback(
    const float* __restrict__ Af, const float* __restrict__ Bf,
    float* __restrict__ out, int M, int N, int K)
{
    __shared__ char sm[32768];
    const int tid  = threadIdx.x;
    const int lane = tid & 63;
    const int w    = tid >> 6;
    const int bm = blockIdx.y, bn = blockIdx.x;
    const int wm = (w >> 1) * 64;
    const int wn = (w & 1) * 64;

    f32x4 acc[4][4] = {};
    const int sfetch = (tid & 3) ^ ((tid >> 3) & 3);
    const int rA = lane & 15;
    const int ca = (lane >> 4) ^ ((lane >> 1) & 3);
    const char* aP = sm +         (wm + rA) * 64 + ca * 16;
    const char* bP = sm + 16384 + (wn + rA) * 64 + ca * 16;

    for (int k0 = 0; k0 < K; k0 += 32) {
        __syncthreads();
#pragma unroll
        for (int c = 0; c < 4; ++c) {
            const bool isA = (c < 2);
            const int row = ((c & 1) << 6) + (tid >> 2);
            const float* src = (isA ? Af + (size_t)(bm * 128 + row) * K
                                    : Bf + (size_t)(bn * 128 + row) * K)
                               + k0 + ((tid & 3) << 3);
            f32x4 v0 = *(const f32x4*)src;
            f32x4 v1 = *(const f32x4*)(src + 4);
            float vv[8] = {v0.x, v0.y, v0.z, v0.w, v1.x, v1.y, v1.z, v1.w};
            bf16x8 h, l;
#pragma unroll
            for (int j = 0; j < 8; ++j) {
                unsigned short hb = f32_to_bf16_rtn(vv[j]);
                unsigned short lb = f32_to_bf16_rtn(vv[j] - bf16_bits_to_f32(hb));
                h[j] = (short)hb; l[j] = (short)lb;
            }
            const int g = row * 64 + sfetch * 16;
            *(bf16x8*)(sm + (isA ? 0 : 16384) + g) = h;
            *(bf16x8*)(sm + (isA ? 8192 : 24576) + g) = l;
        }
        __syncthreads();

        bf16x8 bh[4], bl[4];
#pragma unroll
        for (int j = 0; j < 4; ++j) {
            bh[j] = *(const bf16x8*)(bP + j * 1024);
            bl[j] = *(const bf16x8*)(bP + j * 1024 + 8192);
        }
#pragma unroll
        for (int i = 0; i < 4; ++i) {
            bf16x8 ah = *(const bf16x8*)(aP + i * 1024);
            bf16x8 al = *(const bf16x8*)(aP + i * 1024 + 8192);
#pragma unroll
            for (int j = 0; j < 4; ++j) {
                acc[i][j] = __builtin_amdgcn_mfma_f32_16x16x32_bf16(ah, bh[j], acc[i][j], 0, 0, 0);
                acc[i][j] = __builtin_amdgcn_mfma_f32_16x16x32_bf16(al, bh[j], acc[i][j], 0, 0, 0);
                acc[i][j] = __builtin_amdgcn_mfma_f32_16x16x32_bf16(ah, bl[j], acc[i][j], 0, 0, 0);
            }
        }
    }

    const int r0 = bm * 128 + wm + ((lane >> 4) << 2);
    const int c0 = bn * 128 + wn + rA;
#pragma unroll
    for (int i = 0; i < 4; ++i)
#pragma unroll
        for (int j = 0; j < 4; ++j)
#pragma unroll
            for (int r = 0; r < 4; ++r)
                out[(size_t)(r0 + i * 16 + r) * N + (c0 + j * 16)] = acc[i][j][r];
}

// ---------------------------------------------------------------------------
// Kernel 3: in-place row softmax, SOFTWARE-PIPELINED rows.
// 2048 blocks x 256 threads; each block owns 4 consecutive rows of 8192 f32.
// NEW this round: row rr+1's 8 global loads are issued BEFORE row rr's
// reductions consume va (compiler waits at vmcnt(8), keeping the prefetch in
// flight across both shfl chains, the exp pass and both barriers), and the
// LDS reduce slots are double-buffered (slot = rr&1) so the trailing
// __syncthreads per row is gone (3 -> 2 barriers/row). Identical arithmetic
// and reduction order to the previous version -> bit-identical output.
// ---------------------------------------------------------------------------
__device__ __forceinline__ void softmax_row(
    f32x4 (&v)[8], f32x4 (&vn)[8], const f32x4* __restrict__ pn, bool pref,
    f32x4* __restrict__ pout, int tid, int slot,
    float (*smax)[4], float (*ssum)[4])
{
    if (pref) {
#pragma unroll
        for (int i = 0; i < 8; ++i) vn[i] = pn[tid + (i << 8)];
    }
    float m = -3.402823466e+38f;
#pragma unroll
    for (int i = 0; i < 8; ++i)
        m = fmaxf(m, fmaxf(fmaxf(v[i].x, v[i].y), fmaxf(v[i].z, v[i].w)));
#pragma unroll
    for (int o = 32; o >= 1; o >>= 1) m = fmaxf(m, __shfl_xor(m, o));
    if ((tid & 63) == 0) smax[slot][tid >> 6] = m;
    __syncthreads();
    m = fmaxf(fmaxf(smax[slot][0], smax[slot][1]), fmaxf(smax[slot][2], smax[slot][3]));

    float s = 0.f;
#pragma unroll
    for (int i = 0; i < 8; ++i) {
        v[i].x = __expf(v[i].x - m);
        v[i].y = __expf(v[i].y - m);
        v[i].z = __expf(v[i].z - m);
        v[i].w = __expf(v[i].w - m);
        s += (v[i].x + v[i].y) + (v[i].z + v[i].w);
    }
#pragma unroll
    for (int o = 32; o >= 1; o >>= 1) s += __shfl_xor(s, o);
    if ((tid & 63) == 0) ssum[slot][tid >> 6] = s;
    __syncthreads();
    s = (ssum[slot][0] + ssum[slot][1]) + (ssum[slot][2] + ssum[slot][3]);
    const float r = 1.0f / s;
#pragma unroll
    for (int i = 0; i < 8; ++i) {
        v[i] *= r;
        __builtin_nontemporal_store(v[i], &pout[tid + (i << 8)]);
    }
}

__global__ __launch_bounds__(256) void softmax_rows_8192(float* __restrict__ d)
{
    const int tid = threadIdx.x;
    __shared__ float smax[2][4], ssum[2][4];

    f32x4* p0 = (f32x4*)(d + (size_t)blockIdx.x * 4 * 8192);
    f32x4 va[8], vb[8];
#pragma unroll
    for (int i = 0; i < 8; ++i) va[i] = p0[tid + (i << 8)];

    softmax_row(va, vb, p0 + 2048, true,  p0,        tid, 0, smax, ssum);
    softmax_row(vb, va, p0 + 4096, true,  p0 + 2048, tid, 1, smax, ssum);
    softmax_row(va, vb, p0 + 6144, true,  p0 + 4096, tid, 0, smax, ssum);
    softmax_row(vb, va, p0,        false, p0 + 6144, tid, 1, smax, ssum);
}

// ---------------------------------------------------------------------------
extern "C" void kernel_launch(void* const* d_in, const int* in_sizes, int n_in,
                              void* d_out, int out_size, void* d_ws, size_t ws_size,
                              hipStream_t stream)
{
    const float* A = (const float*)d_in[0];   // user_emb [M, K] fp32
    const float* B = (const float*)d_in[1];   // id_emb   [N, K] fp32
    float* out = (float*)d_out;               // [M, N] fp32
    const int K = 1024;
    const int M = in_sizes[0] / K;
    const int N = in_sizes[1] / K;
    const size_t elemsA = (size_t)M * K;
    const size_t elemsB = (size_t)N * K;
    const size_t need = 2 * (elemsA + elemsB) * sizeof(unsigned short);

    dim3 grid(N / 128, M / 128);
    const bool presplit = (ws_size >= need) && (M == N);

    if (presplit) {
        unsigned short* Ahi = (unsigned short*)d_ws;
        unsigned short* Alo = Ahi + elemsA;
        unsigned short* Bhi = Alo + elemsA;
        unsigned short* Blo = Bhi + elemsB;
        const int n4 = (int)(elemsA / 4);
        split_hi_lo<<<(n4 + 255) / 256, 256, 0, stream>>>(A, B, Ahi, Alo, Bhi, Blo, n4);
        gemm_presplit<<<grid, 256, 0, stream>>>(
            (const __hip_bfloat16*)Ahi, (const __hip_bfloat16*)Alo,
            (const __hip_bfloat16*)Bhi, (const __hip_bfloat16*)Blo,
            out, M, N, K);
    } else {
        gemm_fallback<<<grid, 256, 0, stream>>>(A, B, out, M, N, K);
    }
    softmax_rows_8192<<<M / 4, 256, 0, stream>>>(out);
}

// Round 3
// 754.795 us; speedup vs baseline: 1.0314x; 1.0314x over previous
//
#include <hip/hip_runtime.h>
#include <hip/hip_bf16.h>
#include <stdint.h>

typedef __attribute__((ext_vector_type(8))) short bf16x8;
typedef __attribute__((ext_vector_type(4))) float f32x4;

typedef const __attribute__((address_space(1))) void* gas_ptr;
typedef __attribute__((address_space(3))) void* lds_ptr_t;

__device__ __forceinline__ unsigned short f32_to_bf16_rtn(float x) {
    unsigned u = __float_as_uint(x);
    u += 0x7FFFu + ((u >> 16) & 1u);
    return (unsigned short)(u >> 16);
}
__device__ __forceinline__ float bf16_bits_to_f32(unsigned short h) {
    return __uint_as_float(((unsigned)h) << 16);
}

// ---------------------------------------------------------------------------
// Kernel 1: split fp32 inputs into hi/lo bf16 pairs (a = hi + lo, err ~2^-17)
// ---------------------------------------------------------------------------
__global__ __launch_bounds__(256) void split_hi_lo(
    const float* __restrict__ A, const float* __restrict__ B,
    unsigned short* __restrict__ Ahi, unsigned short* __restrict__ Alo,
    unsigned short* __restrict__ Bhi, unsigned short* __restrict__ Blo, int n4)
{
    int i = blockIdx.x * 256 + threadIdx.x;
    if (i >= n4) return;
    float4 a = ((const float4*)A)[i];
    float4 b = ((const float4*)B)[i];
    ushort4 h, l;

    h.x = f32_to_bf16_rtn(a.x); l.x = f32_to_bf16_rtn(a.x - bf16_bits_to_f32(h.x));
    h.y = f32_to_bf16_rtn(a.y); l.y = f32_to_bf16_rtn(a.y - bf16_bits_to_f32(h.y));
    h.z = f32_to_bf16_rtn(a.z); l.z = f32_to_bf16_rtn(a.z - bf16_bits_to_f32(h.z));
    h.w = f32_to_bf16_rtn(a.w); l.w = f32_to_bf16_rtn(a.w - bf16_bits_to_f32(h.w));
    ((ushort4*)Ahi)[i] = h; ((ushort4*)Alo)[i] = l;

    h.x = f32_to_bf16_rtn(b.x); l.x = f32_to_bf16_rtn(b.x - bf16_bits_to_f32(h.x));
    h.y = f32_to_bf16_rtn(b.y); l.y = f32_to_bf16_rtn(b.y - bf16_bits_to_f32(h.y));
    h.z = f32_to_bf16_rtn(b.z); l.z = f32_to_bf16_rtn(b.z - bf16_bits_to_f32(h.z));
    h.w = f32_to_bf16_rtn(b.w); l.w = f32_to_bf16_rtn(b.w - bf16_bits_to_f32(h.w));
    ((ushort4*)Bhi)[i] = h; ((ushort4*)Blo)[i] = l;
}

// ---------------------------------------------------------------------------
// Kernel 2 (presplit, hot path): energies = A @ B^T, split-bf16 3-product GEMM.
// 16x16x32 mfma, 4x4 tiles/wave, 128x128 block, BK=32.
// XOR swizzle on 16B chunks: SQ_LDS_BANK_CONFLICT == 0 measured (r4).
// NO min-waves launch bound (r4: forced 128-reg budget -> spills, -470 us).
// NO XCD blockIdx swizzle: r1 measured FETCH_SIZE 323 MB -> 1.4 GB (4.3x) and
// MfmaUtil 52 -> 37 with the chunked remap (concurrent per-XCD blocks spanned
// all 64 bm-panels -> 4 MB L2 thrash). Natural dispatch order wins here.
// ---------------------------------------------------------------------------
__global__ __launch_bounds__(256) void gemm_presplit(
    const __hip_bfloat16* __restrict__ Ahi, const __hip_bfloat16* __restrict__ Alo,
    const __hip_bfloat16* __restrict__ Bhi, const __hip_bfloat16* __restrict__ Blo,
    float* __restrict__ out, int M, int N, int K)
{
    __shared__ char sm[32768];   // [0,8K)=Ahi [8K,16K)=Alo [16K,24K)=Bhi [24K,32K)=Blo
    const int tid  = threadIdx.x;
    const int lane = tid & 63;
    const int w    = tid >> 6;
    const int bm = blockIdx.y, bn = blockIdx.x;
    const int wm = (w >> 1) * 64;
    const int wn = (w & 1) * 64;

    f32x4 acc[4][4] = {};

    // staging: thread owns LDS chunk (row=(c&1)*64 + tid>>2, pos=tid&3);
    // fetches source chunk (tid&3) ^ ((row>>1)&3) = (tid&3) ^ ((tid>>3)&3)
    const int sfetch = (tid & 3) ^ ((tid >> 3) & 3);
    const size_t offA = (size_t)(bm * 128 + (tid >> 2)) * K + sfetch * 8;
    const size_t offB = (size_t)(bn * 128 + (tid >> 2)) * K + sfetch * 8;
    const __hip_bfloat16* pAh = Ahi + offA;
    const __hip_bfloat16* pAl = Alo + offA;
    const __hip_bfloat16* pBh = Bhi + offB;
    const __hip_bfloat16* pBl = Blo + offB;
    const size_t half = (size_t)64 * K;   // +64 rows
    char* dst0 = sm + tid * 16;

    // read side: fragment chunk = lane>>4, swizzled: ^ ((lane>>1)&3)
    const int rA = lane & 15;
    const int ca = (lane >> 4) ^ ((lane >> 1) & 3);
    const char* aP = sm +         (wm + rA) * 64 + ca * 16;   // A-hi base
    const char* bP = sm + 16384 + (wn + rA) * 64 + ca * 16;   // B-hi base

    for (int k0 = 0; k0 < K; k0 += 32) {
        __syncthreads();
        __builtin_amdgcn_global_load_lds((gas_ptr)(pAh + k0),        (lds_ptr_t)(dst0),         16, 0, 0);
        __builtin_amdgcn_global_load_lds((gas_ptr)(pAh + half + k0), (lds_ptr_t)(dst0 + 4096),  16, 0, 0);
        __builtin_amdgcn_global_load_lds((gas_ptr)(pAl + k0),        (lds_ptr_t)(dst0 + 8192),  16, 0, 0);
        __builtin_amdgcn_global_load_lds((gas_ptr)(pAl + half + k0), (lds_ptr_t)(dst0 + 12288), 16, 0, 0);
        __builtin_amdgcn_global_load_lds((gas_ptr)(pBh + k0),        (lds_ptr_t)(dst0 + 16384), 16, 0, 0);
        __builtin_amdgcn_global_load_lds((gas_ptr)(pBh + half + k0), (lds_ptr_t)(dst0 + 20480), 16, 0, 0);
        __builtin_amdgcn_global_load_lds((gas_ptr)(pBl + k0),        (lds_ptr_t)(dst0 + 24576), 16, 0, 0);
        __builtin_amdgcn_global_load_lds((gas_ptr)(pBl + half + k0), (lds_ptr_t)(dst0 + 28672), 16, 0, 0);
        __syncthreads();

        bf16x8 bh[4], bl[4];
#pragma unroll
        for (int j = 0; j < 4; ++j) {
            bh[j] = *(const bf16x8*)(bP + j * 1024);
            bl[j] = *(const bf16x8*)(bP + j * 1024 + 8192);
        }
#pragma unroll
        for (int i = 0; i < 4; ++i) {
            bf16x8 ah = *(const bf16x8*)(aP + i * 1024);
            bf16x8 al = *(const bf16x8*)(aP + i * 1024 + 8192);
#pragma unroll
            for (int j = 0; j < 4; ++j) {
                acc[i][j] = __builtin_amdgcn_mfma_f32_16x16x32_bf16(ah, bh[j], acc[i][j], 0, 0, 0);
                acc[i][j] = __builtin_amdgcn_mfma_f32_16x16x32_bf16(al, bh[j], acc[i][j], 0, 0, 0);
                acc[i][j] = __builtin_amdgcn_mfma_f32_16x16x32_bf16(ah, bl[j], acc[i][j], 0, 0, 0);
            }
        }
    }

    // Epilogue: 16x16 C/D layout col=lane&15, row=(lane>>4)*4+reg (m89/m91)
    const int r0 = bm * 128 + wm + ((lane >> 4) << 2);
    const int c0 = bn * 128 + wn + rA;
#pragma unroll
    for (int i = 0; i < 4; ++i)
#pragma unroll
        for (int j = 0; j < 4; ++j)
#pragma unroll
            for (int r = 0; r < 4; ++r)
                out[(size_t)(r0 + i * 16 + r) * N + (c0 + j * 16)] = acc[i][j][r];
}

// ---------------------------------------------------------------------------
// Kernel 2b (fallback, ws too small — not expected to run): inline split.
// ---------------------------------------------------------------------------
__global__ __launch_bounds__(256) void gemm_fallback(
    const float* __restrict__ Af, const float* __restrict__ Bf,
    float* __restrict__ out, int M, int N, int K)
{
    __shared__ char sm[32768];
    const int tid  = threadIdx.x;
    const int lane = tid & 63;
    const int w    = tid >> 6;
    const int bm = blockIdx.y, bn = blockIdx.x;
    const int wm = (w >> 1) * 64;
    const int wn = (w & 1) * 64;

    f32x4 acc[4][4] = {};
    const int sfetch = (tid & 3) ^ ((tid >> 3) & 3);
    const int rA = lane & 15;
    const int ca = (lane >> 4) ^ ((lane >> 1) & 3);
    const char* aP = sm +         (wm + rA) * 64 + ca * 16;
    const char* bP = sm + 16384 + (wn + rA) * 64 + ca * 16;

    for (int k0 = 0; k0 < K; k0 += 32) {
        __syncthreads();
#pragma unroll
        for (int c = 0; c < 4; ++c) {
            const bool isA = (c < 2);
            const int row = ((c & 1) << 6) + (tid >> 2);
            const float* src = (isA ? Af + (size_t)(bm * 128 + row) * K
                                    : Bf + (size_t)(bn * 128 + row) * K)
                               + k0 + ((tid & 3) << 3);
            f32x4 v0 = *(const f32x4*)src;
            f32x4 v1 = *(const f32x4*)(src + 4);
            float vv[8] = {v0.x, v0.y, v0.z, v0.w, v1.x, v1.y, v1.z, v1.w};
            bf16x8 h, l;
#pragma unroll
            for (int j = 0; j < 8; ++j) {
                unsigned short hb = f32_to_bf16_rtn(vv[j]);
                unsigned short lb = f32_to_bf16_rtn(vv[j] - bf16_bits_to_f32(hb));
                h[j] = (short)hb; l[j] = (short)lb;
            }
            const int g = row * 64 + sfetch * 16;
            *(bf16x8*)(sm + (isA ? 0 : 16384) + g) = h;
            *(bf16x8*)(sm + (isA ? 8192 : 24576) + g) = l;
        }
        __syncthreads();

        bf16x8 bh[4], bl[4];
#pragma unroll
        for (int j = 0; j < 4; ++j) {
            bh[j] = *(const bf16x8*)(bP + j * 1024);
            bl[j] = *(const bf16x8*)(bP + j * 1024 + 8192);
        }
#pragma unroll
        for (int i = 0; i < 4; ++i) {
            bf16x8 ah = *(const bf16x8*)(aP + i * 1024);
            bf16x8 al = *(const bf16x8*)(aP + i * 1024 + 8192);
#pragma unroll
            for (int j = 0; j < 4; ++j) {
                acc[i][j] = __builtin_amdgcn_mfma_f32_16x16x32_bf16(ah, bh[j], acc[i][j], 0, 0, 0);
                acc[i][j] = __builtin_amdgcn_mfma_f32_16x16x32_bf16(al, bh[j], acc[i][j], 0, 0, 0);
                acc[i][j] = __builtin_amdgcn_mfma_f32_16x16x32_bf16(ah, bl[j], acc[i][j], 0, 0, 0);
            }
        }
    }

    const int r0 = bm * 128 + wm + ((lane >> 4) << 2);
    const int c0 = bn * 128 + wn + rA;
#pragma unroll
    for (int i = 0; i < 4; ++i)
#pragma unroll
        for (int j = 0; j < 4; ++j)
#pragma unroll
            for (int r = 0; r < 4; ++r)
                out[(size_t)(r0 + i * 16 + r) * N + (c0 + j * 16)] = acc[i][j][r];
}

// ---------------------------------------------------------------------------
// Kernel 3: in-place row softmax, pipelined rows + LGKM-ONLY BARRIERS.
// r1 lesson: __syncthreads() compiles to `s_waitcnt vmcnt(0) ... ; s_barrier`
// (m97 asm evidence) -> each row's reduce barriers DRAINED the row+1 prefetch
// loads and the row-1 NT stores, so the r1 pipeline bought nothing. The only
// cross-wave data here is 4 floats in smax/ssum (LDS), which needs lgkmcnt(0)
// only. Raw s_barrier + lgkm wait leaves the 8 prefetch loads + 8 NT stores
// in flight across both barriers (T4's counted-vmcnt idea, N=unbounded).
// Slots double-buffered (slot=row&1) -> no trailing barrier. All 256 threads
// reach every barrier uniformly; in-place rows touched exactly once; asm
// "memory" fences on both sides pin LDS/global op motion (rule #18).
// ---------------------------------------------------------------------------
__device__ __forceinline__ void lgkm_barrier()
{
    asm volatile("s_waitcnt lgkmcnt(0)" ::: "memory");
    __builtin_amdgcn_s_barrier();
    asm volatile("" ::: "memory");
}

__device__ __forceinline__ void softmax_row(
    f32x4 (&v)[8], f32x4 (&vn)[8], const f32x4* __restrict__ pn, bool pref,
    f32x4* __restrict__ pout, int tid, int slot,
    float (*smax)[4], float (*ssum)[4])
{
    if (pref) {
#pragma unroll
        for (int i = 0; i < 8; ++i) vn[i] = pn[tid + (i << 8)];
    }
    float m = -3.402823466e+38f;
#pragma unroll
    for (int i = 0; i < 8; ++i)
        m = fmaxf(m, fmaxf(fmaxf(v[i].x, v[i].y), fmaxf(v[i].z, v[i].w)));
#pragma unroll
    for (int o = 32; o >= 1; o >>= 1) m = fmaxf(m, __shfl_xor(m, o));
    if ((tid & 63) == 0) smax[slot][tid >> 6] = m;
    lgkm_barrier();
    m = fmaxf(fmaxf(smax[slot][0], smax[slot][1]), fmaxf(smax[slot][2], smax[slot][3]));

    float s = 0.f;
#pragma unroll
    for (int i = 0; i < 8; ++i) {
        v[i].x = __expf(v[i].x - m);
        v[i].y = __expf(v[i].y - m);
        v[i].z = __expf(v[i].z - m);
        v[i].w = __expf(v[i].w - m);
        s += (v[i].x + v[i].y) + (v[i].z + v[i].w);
    }
#pragma unroll
    for (int o = 32; o >= 1; o >>= 1) s += __shfl_xor(s, o);
    if ((tid & 63) == 0) ssum[slot][tid >> 6] = s;
    lgkm_barrier();
    s = (ssum[slot][0] + ssum[slot][1]) + (ssum[slot][2] + ssum[slot][3]);
    const float r = 1.0f / s;
#pragma unroll
    for (int i = 0; i < 8; ++i) {
        v[i] *= r;
        __builtin_nontemporal_store(v[i], &pout[tid + (i << 8)]);
    }
}

__global__ __launch_bounds__(256) void softmax_rows_8192(float* __restrict__ d)
{
    const int tid = threadIdx.x;
    __shared__ float smax[2][4], ssum[2][4];

    f32x4* p0 = (f32x4*)(d + (size_t)blockIdx.x * 4 * 8192);
    f32x4 va[8], vb[8];
#pragma unroll
    for (int i = 0; i < 8; ++i) va[i] = p0[tid + (i << 8)];

    softmax_row(va, vb, p0 + 2048, true,  p0,        tid, 0, smax, ssum);
    softmax_row(vb, va, p0 + 4096, true,  p0 + 2048, tid, 1, smax, ssum);
    softmax_row(va, vb, p0 + 6144, true,  p0 + 4096, tid, 0, smax, ssum);
    softmax_row(vb, va, p0,        false, p0 + 6144, tid, 1, smax, ssum);
}

// ---------------------------------------------------------------------------
extern "C" void kernel_launch(void* const* d_in, const int* in_sizes, int n_in,
                              void* d_out, int out_size, void* d_ws, size_t ws_size,
                              hipStream_t stream)
{
    const float* A = (const float*)d_in[0];   // user_emb [M, K] fp32
    const float* B = (const float*)d_in[1];   // id_emb   [N, K] fp32
    float* out = (float*)d_out;               // [M, N] fp32
    const int K = 1024;
    const int M = in_sizes[0] / K;
    const int N = in_sizes[1] / K;
    const size_t elemsA = (size_t)M * K;
    const size_t elemsB = (size_t)N * K;
    const size_t need = 2 * (elemsA + elemsB) * sizeof(unsigned short);

    dim3 grid(N / 128, M / 128);
    const bool presplit = (ws_size >= need) && (M == N);

    if (presplit) {
        unsigned short* Ahi = (unsigned short*)d_ws;
        unsigned short* Alo = Ahi + elemsA;
        unsigned short* Bhi = Alo + elemsA;
        unsigned short* Blo = Bhi + elemsB;
        const int n4 = (int)(elemsA / 4);
        split_hi_lo<<<(n4 + 255) / 256, 256, 0, stream>>>(A, B, Ahi, Alo, Bhi, Blo, n4);
        gemm_presplit<<<grid, 256, 0, stream>>>(
            (const __hip_bfloat16*)Ahi, (const __hip_bfloat16*)Alo,
            (const __hip_bfloat16*)Bhi, (const __hip_bfloat16*)Blo,
            out, M, N, K);
    } else {
        gemm_fallback<<<grid, 256, 0, stream>>>(A, B, out, M, N, K);
    }
    softmax_rows_8192<<<M / 4, 256, 0, stream>>>(out);
}

// Round 4
// 718.705 us; speedup vs baseline: 1.0831x; 1.0502x over previous
//
#include <hip/hip_runtime.h>
#include <hip/hip_bf16.h>
#include <stdint.h>

typedef __attribute__((ext_vector_type(8))) short bf16x8;
typedef __attribute__((ext_vector_type(4))) float f32x4;

typedef const __attribute__((address_space(1))) void* gas_ptr;
typedef __attribute__((address_space(3))) void* lds_ptr_t;

__device__ __forceinline__ unsigned short f32_to_bf16_rtn(float x) {
    unsigned u = __float_as_uint(x);
    u += 0x7FFFu + ((u >> 16) & 1u);
    return (unsigned short)(u >> 16);
}
__device__ __forceinline__ float bf16_bits_to_f32(unsigned short h) {
    return __uint_as_float(((unsigned)h) << 16);
}

// ---------------------------------------------------------------------------
// Kernel 1: split fp32 inputs into hi/lo bf16 pairs (a = hi + lo, err ~2^-17)
// ---------------------------------------------------------------------------
__global__ __launch_bounds__(256) void split_hi_lo(
    const float* __restrict__ A, const float* __restrict__ B,
    unsigned short* __restrict__ Ahi, unsigned short* __restrict__ Alo,
    unsigned short* __restrict__ Bhi, unsigned short* __restrict__ Blo, int n4)
{
    int i = blockIdx.x * 256 + threadIdx.x;
    if (i >= n4) return;
    float4 a = ((const float4*)A)[i];
    float4 b = ((const float4*)B)[i];
    ushort4 h, l;

    h.x = f32_to_bf16_rtn(a.x); l.x = f32_to_bf16_rtn(a.x - bf16_bits_to_f32(h.x));
    h.y = f32_to_bf16_rtn(a.y); l.y = f32_to_bf16_rtn(a.y - bf16_bits_to_f32(h.y));
    h.z = f32_to_bf16_rtn(a.z); l.z = f32_to_bf16_rtn(a.z - bf16_bits_to_f32(h.z));
    h.w = f32_to_bf16_rtn(a.w); l.w = f32_to_bf16_rtn(a.w - bf16_bits_to_f32(h.w));
    ((ushort4*)Ahi)[i] = h; ((ushort4*)Alo)[i] = l;

    h.x = f32_to_bf16_rtn(b.x); l.x = f32_to_bf16_rtn(b.x - bf16_bits_to_f32(h.x));
    h.y = f32_to_bf16_rtn(b.y); l.y = f32_to_bf16_rtn(b.y - bf16_bits_to_f32(h.y));
    h.z = f32_to_bf16_rtn(b.z); l.z = f32_to_bf16_rtn(b.z - bf16_bits_to_f32(h.z));
    h.w = f32_to_bf16_rtn(b.w); l.w = f32_to_bf16_rtn(b.w - bf16_bits_to_f32(h.w));
    ((ushort4*)Bhi)[i] = h; ((ushort4*)Blo)[i] = l;
}

// ---------------------------------------------------------------------------
// Kernel 2 (presplit, hot path): energies = A @ B^T, split-bf16 3-product GEMM.
// 16x16x32 mfma, 4x4 tiles/wave, 128x128 block, BK=32.
// XOR swizzle on 16B chunks: SQ_LDS_BANK_CONFLICT == 0 measured (r4, prev
// session). NO min-waves launch bound (forced 128-reg budget -> spills).
// NO XCD blockIdx swizzle: r1 measured FETCH 323 MB -> 1.4 GB, MfmaUtil 52->37.
// r4 THIS SESSION: compile-time dims (KC=1024, NC=8192 template) + K-loop
// unroll x4. Theory: SIMD issue port is ~95% busy (MfmaUtil 52 + VALUBusy 43);
// runtime-K loop re-does 8 per-lane 64-bit addr adds per K-step for the
// global_load_lds. With constexpr dims + unroll, per-step offsets (0/64/128/
// 192 B) fold into the 13-bit global_load_lds immediate -> ~3/4 of staging
// addr VALU + loop bookkeeping gone. Predict VALUBusy 43 -> ~30, MfmaUtil
// 52 -> ~60. Same math, same FP order, same LDS/swizzle -> absmax unchanged.
// ---------------------------------------------------------------------------
template<int KC, int NC>
__global__ __launch_bounds__(256) void gemm_presplit(
    const __hip_bfloat16* __restrict__ Ahi, const __hip_bfloat16* __restrict__ Alo,
    const __hip_bfloat16* __restrict__ Bhi, const __hip_bfloat16* __restrict__ Blo,
    float* __restrict__ out, int M, int N, int K)
{
    const int Kd = (KC > 0) ? KC : K;   // compile-time when KC>0
    const int Nd = (NC > 0) ? NC : N;

    __shared__ char sm[32768];   // [0,8K)=Ahi [8K,16K)=Alo [16K,24K)=Bhi [24K,32K)=Blo
    const int tid  = threadIdx.x;
    const int lane = tid & 63;
    const int w    = tid >> 6;
    const int bm = blockIdx.y, bn = blockIdx.x;
    const int wm = (w >> 1) * 64;
    const int wn = (w & 1) * 64;

    f32x4 acc[4][4] = {};

    // staging: thread owns LDS chunk (row=(c&1)*64 + tid>>2, pos=tid&3);
    // fetches source chunk (tid&3) ^ ((row>>1)&3) = (tid&3) ^ ((tid>>3)&3)
    const int sfetch = (tid & 3) ^ ((tid >> 3) & 3);
    const size_t offA = (size_t)(bm * 128 + (tid >> 2)) * Kd + sfetch * 8;
    const size_t offB = (size_t)(bn * 128 + (tid >> 2)) * Kd + sfetch * 8;
    const __hip_bfloat16* pAh = Ahi + offA;
    const __hip_bfloat16* pAl = Alo + offA;
    const __hip_bfloat16* pBh = Bhi + offB;
    const __hip_bfloat16* pBl = Blo + offB;
    const size_t half = (size_t)64 * Kd;   // +64 rows
    char* dst0 = sm + tid * 16;

    // read side: fragment chunk = lane>>4, swizzled: ^ ((lane>>1)&3)
    const int rA = lane & 15;
    const int ca = (lane >> 4) ^ ((lane >> 1) & 3);
    const char* aP = sm +         (wm + rA) * 64 + ca * 16;   // A-hi base
    const char* bP = sm + 16384 + (wn + rA) * 64 + ca * 16;   // B-hi base

#pragma unroll 4
    for (int k0 = 0; k0 < Kd; k0 += 32) {
        __syncthreads();
        __builtin_amdgcn_global_load_lds((gas_ptr)(pAh + k0),        (lds_ptr_t)(dst0),         16, 0, 0);
        __builtin_amdgcn_global_load_lds((gas_ptr)(pAh + half + k0), (lds_ptr_t)(dst0 + 4096),  16, 0, 0);
        __builtin_amdgcn_global_load_lds((gas_ptr)(pAl + k0),        (lds_ptr_t)(dst0 + 8192),  16, 0, 0);
        __builtin_amdgcn_global_load_lds((gas_ptr)(pAl + half + k0), (lds_ptr_t)(dst0 + 12288), 16, 0, 0);
        __builtin_amdgcn_global_load_lds((gas_ptr)(pBh + k0),        (lds_ptr_t)(dst0 + 16384), 16, 0, 0);
        __builtin_amdgcn_global_load_lds((gas_ptr)(pBh + half + k0), (lds_ptr_t)(dst0 + 20480), 16, 0, 0);
        __builtin_amdgcn_global_load_lds((gas_ptr)(pBl + k0),        (lds_ptr_t)(dst0 + 24576), 16, 0, 0);
        __builtin_amdgcn_global_load_lds((gas_ptr)(pBl + half + k0), (lds_ptr_t)(dst0 + 28672), 16, 0, 0);
        __syncthreads();

        bf16x8 bh[4], bl[4];
#pragma unroll
        for (int j = 0; j < 4; ++j) {
            bh[j] = *(const bf16x8*)(bP + j * 1024);
            bl[j] = *(const bf16x8*)(bP + j * 1024 + 8192);
        }
#pragma unroll
        for (int i = 0; i < 4; ++i) {
            bf16x8 ah = *(const bf16x8*)(aP + i * 1024);
            bf16x8 al = *(const bf16x8*)(aP + i * 1024 + 8192);
#pragma unroll
            for (int j = 0; j < 4; ++j) {
                acc[i][j] = __builtin_amdgcn_mfma_f32_16x16x32_bf16(ah, bh[j], acc[i][j], 0, 0, 0);
                acc[i][j] = __builtin_amdgcn_mfma_f32_16x16x32_bf16(al, bh[j], acc[i][j], 0, 0, 0);
                acc[i][j] = __builtin_amdgcn_mfma_f32_16x16x32_bf16(ah, bl[j], acc[i][j], 0, 0, 0);
            }
        }
    }

    // Epilogue: 16x16 C/D layout col=lane&15, row=(lane>>4)*4+reg (m89/m91)
    const int r0 = bm * 128 + wm + ((lane >> 4) << 2);
    const int c0 = bn * 128 + wn + rA;
#pragma unroll
    for (int i = 0; i < 4; ++i)
#pragma unroll
        for (int j = 0; j < 4; ++j)
#pragma unroll
            for (int r = 0; r < 4; ++r)
                out[(size_t)(r0 + i * 16 + r) * Nd + (c0 + j * 16)] = acc[i][j][r];
}

// ---------------------------------------------------------------------------
// Kernel 2b (fallback, ws too small — not expected to run): inline split.
// ---------------------------------------------------------------------------
__global__ __launch_bounds__(256) void gemm_fallback(
    const float* __restrict__ Af, const float* __restrict__ Bf,
    float* __restrict__ out, int M, int N, int K)
{
    __shared__ char sm[32768];
    const int tid  = threadIdx.x;
    const int lane = tid & 63;
    const int w    = tid >> 6;
    const int bm = blockIdx.y, bn = blockIdx.x;
    const int wm = (w >> 1) * 64;
    const int wn = (w & 1) * 64;

    f32x4 acc[4][4] = {};
    const int sfetch = (tid & 3) ^ ((tid >> 3) & 3);
    const int rA = lane & 15;
    const int ca = (lane >> 4) ^ ((lane >> 1) & 3);
    const char* aP = sm +         (wm + rA) * 64 + ca * 16;
    const char* bP = sm + 16384 + (wn + rA) * 64 + ca * 16;

    for (int k0 = 0; k0 < K; k0 += 32) {
        __syncthreads();
#pragma unroll
        for (int c = 0; c < 4; ++c) {
            const bool isA = (c < 2);
            const int row = ((c & 1) << 6) + (tid >> 2);
            const float* src = (isA ? Af + (size_t)(bm * 128 + row) * K
                                    : Bf + (size_t)(bn * 128 + row) * K)
                               + k0 + ((tid & 3) << 3);
            f32x4 v0 = *(const f32x4*)src;
            f32x4 v1 = *(const f32x4*)(src + 4);
            float vv[8] = {v0.x, v0.y, v0.z, v0.w, v1.x, v1.y, v1.z, v1.w};
            bf16x8 h, l;
#pragma unroll
            for (int j = 0; j < 8; ++j) {
                unsigned short hb = f32_to_bf16_rtn(vv[j]);
                unsigned short lb = f32_to_bf16_rtn(vv[j] - bf16_bits_to_f32(hb));
                h[j] = (short)hb; l[j] = (short)lb;
            }
            const int g = row * 64 + sfetch * 16;
            *(bf16x8*)(sm + (isA ? 0 : 16384) + g) = h;
            *(bf16x8*)(sm + (isA ? 8192 : 24576) + g) = l;
        }
        __syncthreads();

        bf16x8 bh[4], bl[4];
#pragma unroll
        for (int j = 0; j < 4; ++j) {
            bh[j] = *(const bf16x8*)(bP + j * 1024);
            bl[j] = *(const bf16x8*)(bP + j * 1024 + 8192);
        }
#pragma unroll
        for (int i = 0; i < 4; ++i) {
            bf16x8 ah = *(const bf16x8*)(aP + i * 1024);
            bf16x8 al = *(const bf16x8*)(aP + i * 1024 + 8192);
#pragma unroll
            for (int j = 0; j < 4; ++j) {
                acc[i][j] = __builtin_amdgcn_mfma_f32_16x16x32_bf16(ah, bh[j], acc[i][j], 0, 0, 0);
                acc[i][j] = __builtin_amdgcn_mfma_f32_16x16x32_bf16(al, bh[j], acc[i][j], 0, 0, 0);
                acc[i][j] = __builtin_amdgcn_mfma_f32_16x16x32_bf16(ah, bl[j], acc[i][j], 0, 0, 0);
            }
        }
    }

    const int r0 = bm * 128 + wm + ((lane >> 4) << 2);
    const int c0 = bn * 128 + wn + rA;
#pragma unroll
    for (int i = 0; i < 4; ++i)
#pragma unroll
        for (int j = 0; j < 4; ++j)
#pragma unroll
            for (int r = 0; r < 4; ++r)
                out[(size_t)(r0 + i * 16 + r) * N + (c0 + j * 16)] = acc[i][j][r];
}

// ---------------------------------------------------------------------------
// Kernel 3: in-place row softmax. r0 (3-barrier), r1 (pipeline+syncthreads),
// r3 (pipeline+lgkm-only barriers) all measured the SAME non-gemm remainder
// (~320-350 us) -> softmax-structure theories refuted; remainder is likely
// dominated by harness reset/launch overhead. Keeping the r3 version
// (passed, equal perf). Do not touch further.
// ---------------------------------------------------------------------------
__device__ __forceinline__ void lgkm_barrier()
{
    asm volatile("s_waitcnt lgkmcnt(0)" ::: "memory");
    __builtin_amdgcn_s_barrier();
    asm volatile("" ::: "memory");
}

__device__ __forceinline__ void softmax_row(
    f32x4 (&v)[8], f32x4 (&vn)[8], const f32x4* __restrict__ pn, bool pref,
    f32x4* __restrict__ pout, int tid, int slot,
    float (*smax)[4], float (*ssum)[4])
{
    if (pref) {
#pragma unroll
        for (int i = 0; i < 8; ++i) vn[i] = pn[tid + (i << 8)];
    }
    float m = -3.402823466e+38f;
#pragma unroll
    for (int i = 0; i < 8; ++i)
        m = fmaxf(m, fmaxf(fmaxf(v[i].x, v[i].y), fmaxf(v[i].z, v[i].w)));
#pragma unroll
    for (int o = 32; o >= 1; o >>= 1) m = fmaxf(m, __shfl_xor(m, o));
    if ((tid & 63) == 0) smax[slot][tid >> 6] = m;
    lgkm_barrier();
    m = fmaxf(fmaxf(smax[slot][0], smax[slot][1]), fmaxf(smax[slot][2], smax[slot][3]));

    float s = 0.f;
#pragma unroll
    for (int i = 0; i < 8; ++i) {
        v[i].x = __expf(v[i].x - m);
        v[i].y = __expf(v[i].y - m);
        v[i].z = __expf(v[i].z - m);
        v[i].w = __expf(v[i].w - m);
        s += (v[i].x + v[i].y) + (v[i].z + v[i].w);
    }
#pragma unroll
    for (int o = 32; o >= 1; o >>= 1) s += __shfl_xor(s, o);
    if ((tid & 63) == 0) ssum[slot][tid >> 6] = s;
    lgkm_barrier();
    s = (ssum[slot][0] + ssum[slot][1]) + (ssum[slot][2] + ssum[slot][3]);
    const float r = 1.0f / s;
#pragma unroll
    for (int i = 0; i < 8; ++i) {
        v[i] *= r;
        __builtin_nontemporal_store(v[i], &pout[tid + (i << 8)]);
    }
}

__global__ __launch_bounds__(256) void softmax_rows_8192(float* __restrict__ d)
{
    const int tid = threadIdx.x;
    __shared__ float smax[2][4], ssum[2][4];

    f32x4* p0 = (f32x4*)(d + (size_t)blockIdx.x * 4 * 8192);
    f32x4 va[8], vb[8];
#pragma unroll
    for (int i = 0; i < 8; ++i) va[i] = p0[tid + (i << 8)];

    softmax_row(va, vb, p0 + 2048, true,  p0,        tid, 0, smax, ssum);
    softmax_row(vb, va, p0 + 4096, true,  p0 + 2048, tid, 1, smax, ssum);
    softmax_row(va, vb, p0 + 6144, true,  p0 + 4096, tid, 0, smax, ssum);
    softmax_row(vb, va, p0,        false, p0 + 6144, tid, 1, smax, ssum);
}

// ---------------------------------------------------------------------------
extern "C" void kernel_launch(void* const* d_in, const int* in_sizes, int n_in,
                              void* d_out, int out_size, void* d_ws, size_t ws_size,
                              hipStream_t stream)
{
    const float* A = (const float*)d_in[0];   // user_emb [M, K] fp32
    const float* B = (const float*)d_in[1];   // id_emb   [N, K] fp32
    float* out = (float*)d_out;               // [M, N] fp32
    const int K = 1024;
    const int M = in_sizes[0] / K;
    const int N = in_sizes[1] / K;
    const size_t elemsA = (size_t)M * K;
    const size_t elemsB = (size_t)N * K;
    const size_t need = 2 * (elemsA + elemsB) * sizeof(unsigned short);

    dim3 grid(N / 128, M / 128);
    const bool presplit = (ws_size >= need) && (M == N);

    if (presplit) {
        unsigned short* Ahi = (unsigned short*)d_ws;
        unsigned short* Alo = Ahi + elemsA;
        unsigned short* Bhi = Alo + elemsA;
        unsigned short* Blo = Bhi + elemsB;
        const int n4 = (int)(elemsA / 4);
        split_hi_lo<<<(n4 + 255) / 256, 256, 0, stream>>>(A, B, Ahi, Alo, Bhi, Blo, n4);
        if (K == 1024 && N == 8192) {
            gemm_presplit<1024, 8192><<<grid, 256, 0, stream>>>(
                (const __hip_bfloat16*)Ahi, (const __hip_bfloat16*)Alo,
                (const __hip_bfloat16*)Bhi, (const __hip_bfloat16*)Blo,
                out, M, N, K);
        } else {
            gemm_presplit<0, 0><<<grid, 256, 0, stream>>>(
                (const __hip_bfloat16*)Ahi, (const __hip_bfloat16*)Alo,
                (const __hip_bfloat16*)Bhi, (const __hip_bfloat16*)Blo,
                out, M, N, K);
        }
    } else {
        gemm_fallback<<<grid, 256, 0, stream>>>(A, B, out, M, N, K);
    }
    softmax_rows_8192<<<M / 4, 256, 0, stream>>>(out);
}